// Round 2
// baseline (302.491 us; speedup 1.0000x reference)
//
#include <hip/hip_runtime.h>
#include <hip/hip_bf16.h>

#define DEG 32
#define HID 256

typedef __bf16 bf16_t;
typedef bf16_t bf16x8 __attribute__((ext_vector_type(8)));
typedef float f32x16 __attribute__((ext_vector_type(16)));

__device__ __forceinline__ f32x16 zero16() {
  f32x16 z;
#pragma unroll
  for (int i = 0; i < 16; ++i) z[i] = 0.0f;
  return z;
}

__device__ __forceinline__ float gelu_exact(float x) {
  return 0.5f * x * (1.0f + erff(x * 0.70710678118654752f));
}

// ---- weight prep: fp32 -> bf16, transposed so B-fragments are contiguous in k
__global__ __launch_bounds__(256) void prep_weights(
    const float* __restrict__ w1, const float* __restrict__ w2,
    const float* __restrict__ wp,
    bf16_t* __restrict__ w1T, bf16_t* __restrict__ w2T, bf16_t* __restrict__ wpT) {
  int tid = blockIdx.x * 256 + threadIdx.x;  // 262144 threads
  if (tid < 65536) {
    int n = tid >> 8, k = tid & 255;
    w1T[tid] = (bf16_t)w1[k * 256 + n];
  } else if (tid < 131072) {
    int t = tid - 65536;
    int n = t >> 8, k = t & 255;
    w2T[t] = (bf16_t)w2[k * 256 + n];
  } else if (tid < 262144) {
    int t = tid - 131072;
    int n = t >> 9, k = t & 511;
    wpT[t] = (bf16_t)wp[k * 256 + n];  // wp is (512,256) row-major
  }
}

// ---- per-supernode: embed 32 edges, MLP (MFMA), mean, + supernode embed
__global__ __launch_bounds__(256) void edge_mlp(
    const float* __restrict__ pos, const int* __restrict__ sup_idx,
    const int* __restrict__ src_idx,
    const bf16_t* __restrict__ w1T, const float* __restrict__ b1,
    const bf16_t* __restrict__ w2T, const float* __restrict__ b2,
    bf16_t* __restrict__ cat) {
  __shared__ float rel[DEG][4];
  __shared__ __attribute__((aligned(16))) bf16_t A1[DEG * HID];
  __shared__ __attribute__((aligned(16))) bf16_t A2[DEG * HID];

  const int s = blockIdx.x;
  const int tid = threadIdx.x;
  const int si = sup_idx[s];
  const float spx = pos[si * 3 + 0];
  const float spy = pos[si * 3 + 1];
  const float spz = pos[si * 3 + 2];

  // supernode abs-pos embedding (ndim=3: eff=84, 42 freqs, pad 4) -> cat right half
  {
    float v = 0.0f;
    if (tid < 252) {
      int d = tid / 84;
      int j = tid - d * 84;
      float p = (d == 0) ? spx : ((d == 1) ? spy : spz);
      int jj = (j < 42) ? j : j - 42;
      float om = expf(-(float)jj * 0.21929381838038533f);  // ln(1e4)/42
      float a = p * om;
      v = (j < 42) ? sinf(a) : cosf(a);
    }
    cat[s * 512 + 256 + tid] = (bf16_t)v;
  }

  // per-edge relative position (dx,dy,dz,|d|)
  if (tid < DEG) {
    int e = s * DEG + tid;
    int srci = src_idx[e];
    float dx = spx - pos[srci * 3 + 0];
    float dy = spy - pos[srci * 3 + 1];
    float dz = spz - pos[srci * 3 + 2];
    float mag = sqrtf(dx * dx + dy * dy + dz * dz);
    rel[tid][0] = dx; rel[tid][1] = dy; rel[tid][2] = dz; rel[tid][3] = mag;
  }
  __syncthreads();

  // relpos embedding (ndim=4: eff=64, 32 freqs) into A1, XOR-swizzled bf16
  {
    const int row = tid >> 3;       // edge 0..31
    const int m = tid & 7;          // 32-col block
    const int d = m >> 1;           // input dim 0..3
    const bool is_cos = (m & 1) != 0;
    const float r = rel[row][d];
    const int swz = (row & 7) << 4;
    float om = 1.0f;
    const float step = 0.74989420933324559f;  // 1e4^(-1/32)
#pragma unroll
    for (int i = 0; i < 32; ++i) {
      float a = r * om;
      float v = is_cos ? cosf(a) : sinf(a);
      int col = (m << 5) + i;
      *(bf16_t*)((char*)A1 + row * 512 + ((col * 2) ^ swz)) = (bf16_t)v;
      om *= step;
    }
  }
  __syncthreads();

  const int l = tid & 63;
  const int w = tid >> 6;
  const int arow = l & 31;
  const int asel = l >> 5;
  const int n0 = (w * 2) * 32 + arow;
  const int n1 = (w * 2 + 1) * 32 + arow;
  const int aswz = (arow & 7) << 4;
  const char* A1c = (const char*)A1;
  const char* A2c = (const char*)A2;

  // matmul 1: (32x256) @ w1 -> gelu -> A2
  f32x16 acc0 = zero16(), acc1 = zero16();
#pragma unroll
  for (int kk = 0; kk < 16; ++kk) {
    int k0 = kk * 16 + 8 * asel;
    bf16x8 a = *(const bf16x8*)(A1c + arow * 512 + ((k0 * 2) ^ aswz));
    bf16x8 bb0 = *(const bf16x8*)(w1T + n0 * 256 + k0);
    bf16x8 bb1 = *(const bf16x8*)(w1T + n1 * 256 + k0);
    acc0 = __builtin_amdgcn_mfma_f32_32x32x16_bf16(a, bb0, acc0, 0, 0, 0);
    acc1 = __builtin_amdgcn_mfma_f32_32x32x16_bf16(a, bb1, acc1, 0, 0, 0);
  }
  {
    float bias0 = b1[n0], bias1 = b1[n1];
#pragma unroll
    for (int rr = 0; rr < 16; ++rr) {
      int row = (rr & 3) + 8 * (rr >> 2) + 4 * asel;
      int sw = (row & 7) << 4;
      *(bf16_t*)((char*)A2 + row * 512 + ((n0 * 2) ^ sw)) = (bf16_t)gelu_exact(acc0[rr] + bias0);
      *(bf16_t*)((char*)A2 + row * 512 + ((n1 * 2) ^ sw)) = (bf16_t)gelu_exact(acc1[rr] + bias1);
    }
  }
  __syncthreads();

  // matmul 2: (32x256) @ w2, then mean over the 32 edge rows
  acc0 = zero16(); acc1 = zero16();
#pragma unroll
  for (int kk = 0; kk < 16; ++kk) {
    int k0 = kk * 16 + 8 * asel;
    bf16x8 a = *(const bf16x8*)(A2c + arow * 512 + ((k0 * 2) ^ aswz));
    bf16x8 bb0 = *(const bf16x8*)(w2T + n0 * 256 + k0);
    bf16x8 bb1 = *(const bf16x8*)(w2T + n1 * 256 + k0);
    acc0 = __builtin_amdgcn_mfma_f32_32x32x16_bf16(a, bb0, acc0, 0, 0, 0);
    acc1 = __builtin_amdgcn_mfma_f32_32x32x16_bf16(a, bb1, acc1, 0, 0, 0);
  }
  float s0 = 0.0f, s1 = 0.0f;
#pragma unroll
  for (int rr = 0; rr < 16; ++rr) { s0 += acc0[rr]; s1 += acc1[rr]; }
  s0 += __shfl_xor(s0, 32);
  s1 += __shfl_xor(s1, 32);
  if (l < 32) {
    cat[s * 512 + n0] = (bf16_t)(s0 * 0.03125f + b2[n0]);
    cat[s * 512 + n1] = (bf16_t)(s1 * 0.03125f + b2[n1]);
  }
}

// ---- final projection: (8192x512) @ (512x256) + bp -> out (fp32!)
__global__ __launch_bounds__(256) void proj(
    const bf16_t* __restrict__ cat, const bf16_t* __restrict__ wpT,
    const float* __restrict__ bp, float* __restrict__ out) {
  const int bx = blockIdx.x;  // 64 row-blocks of 128
  const int by = blockIdx.y;  // 2 col-blocks of 128
  const int tid = threadIdx.x;
  const int l = tid & 63;
  const int w = tid >> 6;
  const int wm = w >> 1, wn = w & 1;
  const int rm = bx * 128 + wm * 64;
  const int cn = by * 128 + wn * 64;
  const int asel = l >> 5;
  const int lr = l & 31;

  const int r0 = rm + lr, r1 = rm + 32 + lr;
  const int c0 = cn + lr, c1 = cn + 32 + lr;

  f32x16 a00 = zero16(), a01 = zero16(), a10 = zero16(), a11 = zero16();
#pragma unroll 4
  for (int kk = 0; kk < 32; ++kk) {
    int k0 = kk * 16 + 8 * asel;
    bf16x8 fa0 = *(const bf16x8*)(cat + r0 * 512 + k0);
    bf16x8 fa1 = *(const bf16x8*)(cat + r1 * 512 + k0);
    bf16x8 fb0 = *(const bf16x8*)(wpT + c0 * 512 + k0);
    bf16x8 fb1 = *(const bf16x8*)(wpT + c1 * 512 + k0);
    a00 = __builtin_amdgcn_mfma_f32_32x32x16_bf16(fa0, fb0, a00, 0, 0, 0);
    a01 = __builtin_amdgcn_mfma_f32_32x32x16_bf16(fa0, fb1, a01, 0, 0, 0);
    a10 = __builtin_amdgcn_mfma_f32_32x32x16_bf16(fa1, fb0, a10, 0, 0, 0);
    a11 = __builtin_amdgcn_mfma_f32_32x32x16_bf16(fa1, fb1, a11, 0, 0, 0);
  }
  float bias0 = bp[c0], bias1 = bp[c1];
#pragma unroll
  for (int rr = 0; rr < 16; ++rr) {
    int rowo = (rr & 3) + 8 * (rr >> 2) + 4 * asel;
    out[(rm + rowo) * 256 + c0] = a00[rr] + bias0;
    out[(rm + rowo) * 256 + c1] = a01[rr] + bias1;
    out[(rm + 32 + rowo) * 256 + c0] = a10[rr] + bias0;
    out[(rm + 32 + rowo) * 256 + c1] = a11[rr] + bias1;
  }
}

extern "C" void kernel_launch(void* const* d_in, const int* in_sizes, int n_in,
                              void* d_out, int out_size, void* d_ws, size_t ws_size,
                              hipStream_t stream) {
  const float* pos = (const float*)d_in[0];
  const int* sup_idx = (const int*)d_in[1];
  const int* src_idx = (const int*)d_in[2];
  // d_in[3] = dst_seg: by construction repeat(arange(NSUP), DEG); not needed
  const float* w1 = (const float*)d_in[4];
  const float* b1 = (const float*)d_in[5];
  const float* w2 = (const float*)d_in[6];
  const float* b2 = (const float*)d_in[7];
  const float* wp = (const float*)d_in[8];
  const float* bp = (const float*)d_in[9];

  char* ws = (char*)d_ws;
  bf16_t* w1T = (bf16_t*)(ws);             // 256*256 bf16 = 128 KB
  bf16_t* w2T = (bf16_t*)(ws + 131072);    // 128 KB
  bf16_t* wpT = (bf16_t*)(ws + 262144);    // 256*512 bf16 = 256 KB
  bf16_t* cat = (bf16_t*)(ws + 524288);    // 8192*512 bf16 = 8 MB
  float* out = (float*)d_out;

  if (ws_size < (size_t)(524288 + 8192 * 512 * 2)) return;  // workspace guard

  prep_weights<<<dim3(1024), dim3(256), 0, stream>>>(w1, w2, wp, w1T, w2T, wpT);
  edge_mlp<<<dim3(8192), dim3(256), 0, stream>>>(pos, sup_idx, src_idx, w1T, b1, w2T, b2, cat);
  proj<<<dim3(64, 2), dim3(256), 0, stream>>>(cat, wpT, bp, out);
}

// Round 3
// 134.408 us; speedup vs baseline: 2.2505x; 2.2505x over previous
//
#include <hip/hip_runtime.h>
#include <hip/hip_bf16.h>

#define DEG 32
#define HID 256

typedef __bf16 bf16_t;
typedef bf16_t bf16x8 __attribute__((ext_vector_type(8)));
typedef float f32x16 __attribute__((ext_vector_type(16)));

// 10000^(-i/32), i = 0..31 (compile-time immediates after unroll)
constexpr float OMG[32] = {
    1.0f,           0.74989421f,    0.56234133f,    0.42169650f,
    0.31622777f,    0.23713737f,    0.17782794f,    0.13335214f,
    0.1f,           0.074989421f,   0.056234133f,   0.042169650f,
    0.031622777f,   0.023713737f,   0.017782794f,   0.013335214f,
    0.01f,          0.0074989421f,  0.0056234133f,  0.0042169650f,
    0.0031622777f,  0.0023713737f,  0.0017782794f,  0.0013335214f,
    0.001f,         0.00074989421f, 0.00056234133f, 0.00042169650f,
    0.00031622777f, 0.00023713737f, 0.00017782794f, 0.00013335214f};

__device__ __forceinline__ float gelu_fast(float x) {
  // tanh-form GELU as sigmoid: x * sigma(1.595769*x*(1+0.044715*x^2))
  float u = x * (1.0f + 0.044715f * x * x);
  float e = __expf(-1.5957691216057308f * u);
  return __fdividef(x, 1.0f + e);
}

__device__ __forceinline__ f32x16 mfma_bf16(bf16x8 a, bf16x8 b, f32x16 c) {
  return __builtin_amdgcn_mfma_f32_32x32x16_bf16(a, b, c, 0, 0, 0);
}

// ---- weight prep: fp32 -> bf16, transposed so B-fragments are contiguous in k
__global__ __launch_bounds__(256) void prep_weights(
    const float* __restrict__ w1, const float* __restrict__ w2,
    const float* __restrict__ wp,
    bf16_t* __restrict__ w1T, bf16_t* __restrict__ w2T, bf16_t* __restrict__ wpT) {
  int tid = blockIdx.x * 256 + threadIdx.x;  // 262144 threads
  if (tid < 65536) {
    int n = tid >> 8, k = tid & 255;
    w1T[tid] = (bf16_t)w1[k * 256 + n];
  } else if (tid < 131072) {
    int t = tid - 65536;
    int n = t >> 8, k = t & 255;
    w2T[t] = (bf16_t)w2[k * 256 + n];
  } else if (tid < 262144) {
    int t = tid - 131072;
    int n = t >> 9, k = t & 511;
    wpT[t] = (bf16_t)wp[k * 256 + n];  // wp is (512,256) row-major
  }
}

// ---- 4 supernodes per block: embed 128 edges, MLP (MFMA, M=128), mean
__global__ __launch_bounds__(256, 2) void edge_mlp(
    const float* __restrict__ pos, const int* __restrict__ sup_idx,
    const int* __restrict__ src_idx,
    const bf16_t* __restrict__ w1T, const float* __restrict__ b1,
    const bf16_t* __restrict__ w2T, const float* __restrict__ b2,
    bf16_t* __restrict__ cat) {
  __shared__ __attribute__((aligned(16))) bf16_t A[128 * 256];  // 64 KiB, in-place

  const int bid = blockIdx.x;
  const int tid = threadIdx.x;

  // ---- supernode abs-pos embed (ndim=3: 3*84, 42 freqs, 4 pad) -> cat[.,256:512]
  if (tid < 252) {
    const int j = tid;
    const int d = (j >= 84 ? 1 : 0) + (j >= 168 ? 1 : 0);
    const int jj = j - 84 * d;
    const int sc = (jj >= 42) ? 1 : 0;
    const int i = jj - 42 * sc;
    const float om = __expf(-0.21929381838038533f * (float)i);  // ln(1e4)/42
#pragma unroll
    for (int it = 0; it < 4; ++it) {
      const int srow = bid * 4 + it;
      const float p = pos[sup_idx[srow] * 3 + d];
      const float a = p * om;
      const float v = sc ? __cosf(a) : __sinf(a);
      cat[srow * 512 + 256 + j] = (bf16_t)v;
    }
  } else {
#pragma unroll
    for (int it = 0; it < 4; ++it)
      cat[(bid * 4 + it) * 512 + 256 + tid] = (bf16_t)0.0f;  // pad cols 508..511
  }

  // ---- edge relpos embed (ndim=4: 4*64, 32 freqs) into swizzled A
  {
    const int r = tid >> 1;        // edge row 0..127
    const int h = tid & 1;         // column half (0: cols 0-127, 1: 128-255)
    const int e = bid * 128 + r;
    const int srci = src_idx[e];
    const int si = sup_idx[bid * 4 + (r >> 5)];
    const float dx = pos[si * 3 + 0] - pos[srci * 3 + 0];
    const float dy = pos[si * 3 + 1] - pos[srci * 3 + 1];
    const float dz = pos[si * 3 + 2] - pos[srci * 3 + 2];
    const float mg = sqrtf(dx * dx + dy * dy + dz * dz);
    const float rd0 = h ? dz : dx;  // j<8  -> dim 2h
    const float rd1 = h ? mg : dy;  // j>=8 -> dim 2h+1
    char* arow = (char*)A + r * 512;
    const int swz = (r & 31) << 4;
    const int cb0 = h << 4;
#pragma unroll
    for (int j = 0; j < 16; ++j) {
      const float rd = (j < 8) ? rd0 : rd1;
      bf16x8 v8;
#pragma unroll
      for (int je = 0; je < 8; ++je) {
        const float a = rd * OMG[(j & 3) * 8 + je];
        v8[je] = (bf16_t)(((j >> 2) & 1) ? __cosf(a) : __sinf(a));
      }
      *(bf16x8*)(arow + (((cb0 + j) << 4) ^ swz)) = v8;
    }
  }
  __syncthreads();

  const int l = tid & 63, w = tid >> 6;
  const int hi = l >> 5, lc = l & 31;
  const char* Ab = (const char*)A;
  const int abase = lc * 512;
  const int swzl = lc << 4;

  f32x16 acc[4][2];
#pragma unroll
  for (int mt = 0; mt < 4; ++mt)
#pragma unroll
    for (int nt = 0; nt < 2; ++nt)
#pragma unroll
      for (int q = 0; q < 16; ++q) acc[mt][nt][q] = 0.0f;

  // ---- matmul 1: A(128x256) @ w1 ; wave w owns cols [64w, 64w+64)
  {
    const bf16_t* bp0 = w1T + (64 * w + lc) * 256 + 8 * hi;
    const bf16_t* bp1 = bp0 + 32 * 256;
#pragma unroll
    for (int kk = 0; kk < 16; ++kk) {
      const int koff = abase + ((kk * 32 + hi * 16) ^ swzl);
      bf16x8 a0 = *(const bf16x8*)(Ab + koff);
      bf16x8 a1 = *(const bf16x8*)(Ab + koff + 16384);
      bf16x8 a2 = *(const bf16x8*)(Ab + koff + 32768);
      bf16x8 a3 = *(const bf16x8*)(Ab + koff + 49152);
      bf16x8 f0 = *(const bf16x8*)(bp0 + kk * 16);
      bf16x8 f1 = *(const bf16x8*)(bp1 + kk * 16);
      acc[0][0] = mfma_bf16(a0, f0, acc[0][0]);
      acc[0][1] = mfma_bf16(a0, f1, acc[0][1]);
      acc[1][0] = mfma_bf16(a1, f0, acc[1][0]);
      acc[1][1] = mfma_bf16(a1, f1, acc[1][1]);
      acc[2][0] = mfma_bf16(a2, f0, acc[2][0]);
      acc[2][1] = mfma_bf16(a2, f1, acc[2][1]);
      acc[3][0] = mfma_bf16(a3, f0, acc[3][0]);
      acc[3][1] = mfma_bf16(a3, f1, acc[3][1]);
    }
  }
  __syncthreads();  // all waves done READING A for matmul 1

  // ---- GELU + bias, write back in place (same swizzle)
  {
    const float bi0 = b1[64 * w + lc], bi1 = b1[64 * w + 32 + lc];
    const int c2 = 128 * w + 2 * lc;
    char* Aw = (char*)A;
#pragma unroll
    for (int rr = 0; rr < 16; ++rr) {
      const int rb = (rr & 3) + 8 * (rr >> 2) + 4 * hi;  // row & 31 (mt-independent)
      const int va0 = (rb << 9) + (c2 ^ (rb << 4));
      const int va1 = va0 ^ 64;
#pragma unroll
      for (int mt = 0; mt < 4; ++mt) {
        *(bf16_t*)(Aw + va0 + 16384 * mt) = (bf16_t)gelu_fast(acc[mt][0][rr] + bi0);
        *(bf16_t*)(Aw + va1 + 16384 * mt) = (bf16_t)gelu_fast(acc[mt][1][rr] + bi1);
      }
    }
  }
  __syncthreads();  // gelu writes visible before matmul 2 reads

#pragma unroll
  for (int mt = 0; mt < 4; ++mt)
#pragma unroll
    for (int nt = 0; nt < 2; ++nt)
#pragma unroll
      for (int q = 0; q < 16; ++q) acc[mt][nt][q] = 0.0f;

  // ---- matmul 2: gelu(A) @ w2
  {
    const bf16_t* bp0 = w2T + (64 * w + lc) * 256 + 8 * hi;
    const bf16_t* bp1 = bp0 + 32 * 256;
#pragma unroll
    for (int kk = 0; kk < 16; ++kk) {
      const int koff = abase + ((kk * 32 + hi * 16) ^ swzl);
      bf16x8 a0 = *(const bf16x8*)(Ab + koff);
      bf16x8 a1 = *(const bf16x8*)(Ab + koff + 16384);
      bf16x8 a2 = *(const bf16x8*)(Ab + koff + 32768);
      bf16x8 a3 = *(const bf16x8*)(Ab + koff + 49152);
      bf16x8 f0 = *(const bf16x8*)(bp0 + kk * 16);
      bf16x8 f1 = *(const bf16x8*)(bp1 + kk * 16);
      acc[0][0] = mfma_bf16(a0, f0, acc[0][0]);
      acc[0][1] = mfma_bf16(a0, f1, acc[0][1]);
      acc[1][0] = mfma_bf16(a1, f0, acc[1][0]);
      acc[1][1] = mfma_bf16(a1, f1, acc[1][1]);
      acc[2][0] = mfma_bf16(a2, f0, acc[2][0]);
      acc[2][1] = mfma_bf16(a2, f1, acc[2][1]);
      acc[3][0] = mfma_bf16(a3, f0, acc[3][0]);
      acc[3][1] = mfma_bf16(a3, f1, acc[3][1]);
    }
  }

  // ---- segment mean (exactly 32 edges/supernode) + bias -> cat[.,0:256]
  {
    const float bi0 = b2[64 * w + lc], bi1 = b2[64 * w + 32 + lc];
#pragma unroll
    for (int mt = 0; mt < 4; ++mt) {
      float s0 = 0.0f, s1 = 0.0f;
#pragma unroll
      for (int q = 0; q < 16; ++q) { s0 += acc[mt][0][q]; s1 += acc[mt][1][q]; }
      s0 += __shfl_xor(s0, 32);
      s1 += __shfl_xor(s1, 32);
      if (l < 32) {
        const int srow = bid * 4 + mt;
        cat[srow * 512 + 64 * w + lc] = (bf16_t)(s0 * 0.03125f + bi0);
        cat[srow * 512 + 64 * w + 32 + lc] = (bf16_t)(s1 * 0.03125f + bi1);
      }
    }
  }
}

// ---- final projection: (8192x512) @ (512x256) + bp -> out (fp32)
__global__ __launch_bounds__(256) void proj(
    const bf16_t* __restrict__ cat, const bf16_t* __restrict__ wpT,
    const float* __restrict__ bp, float* __restrict__ out) {
  const int bx = blockIdx.x;  // 64 row-blocks of 128
  const int by = blockIdx.y;  // 2 col-blocks of 128
  const int tid = threadIdx.x;
  const int l = tid & 63;
  const int w = tid >> 6;
  const int wm = w >> 1, wn = w & 1;
  const int rm = bx * 128 + wm * 64;
  const int cn = by * 128 + wn * 64;
  const int asel = l >> 5;
  const int lr = l & 31;

  const int r0 = rm + lr, r1 = rm + 32 + lr;
  const int c0 = cn + lr, c1 = cn + 32 + lr;

  f32x16 a00, a01, a10, a11;
#pragma unroll
  for (int q = 0; q < 16; ++q) { a00[q] = 0.f; a01[q] = 0.f; a10[q] = 0.f; a11[q] = 0.f; }
#pragma unroll 4
  for (int kk = 0; kk < 32; ++kk) {
    int k0 = kk * 16 + 8 * asel;
    bf16x8 fa0 = *(const bf16x8*)(cat + r0 * 512 + k0);
    bf16x8 fa1 = *(const bf16x8*)(cat + r1 * 512 + k0);
    bf16x8 fb0 = *(const bf16x8*)(wpT + c0 * 512 + k0);
    bf16x8 fb1 = *(const bf16x8*)(wpT + c1 * 512 + k0);
    a00 = mfma_bf16(fa0, fb0, a00);
    a01 = mfma_bf16(fa0, fb1, a01);
    a10 = mfma_bf16(fa1, fb0, a10);
    a11 = mfma_bf16(fa1, fb1, a11);
  }
  float bias0 = bp[c0], bias1 = bp[c1];
#pragma unroll
  for (int rr = 0; rr < 16; ++rr) {
    int rowo = (rr & 3) + 8 * (rr >> 2) + 4 * asel;
    out[(rm + rowo) * 256 + c0] = a00[rr] + bias0;
    out[(rm + rowo) * 256 + c1] = a01[rr] + bias1;
    out[(rm + 32 + rowo) * 256 + c0] = a10[rr] + bias0;
    out[(rm + 32 + rowo) * 256 + c1] = a11[rr] + bias1;
  }
}

extern "C" void kernel_launch(void* const* d_in, const int* in_sizes, int n_in,
                              void* d_out, int out_size, void* d_ws, size_t ws_size,
                              hipStream_t stream) {
  const float* pos = (const float*)d_in[0];
  const int* sup_idx = (const int*)d_in[1];
  const int* src_idx = (const int*)d_in[2];
  // d_in[3] = dst_seg: repeat(arange(NSUP), DEG) by construction; not needed
  const float* w1 = (const float*)d_in[4];
  const float* b1 = (const float*)d_in[5];
  const float* w2 = (const float*)d_in[6];
  const float* b2 = (const float*)d_in[7];
  const float* wp = (const float*)d_in[8];
  const float* bp = (const float*)d_in[9];

  char* ws = (char*)d_ws;
  bf16_t* w1T = (bf16_t*)(ws);             // 128 KB
  bf16_t* w2T = (bf16_t*)(ws + 131072);    // 128 KB
  bf16_t* wpT = (bf16_t*)(ws + 262144);    // 256 KB
  bf16_t* cat = (bf16_t*)(ws + 524288);    // 8192*512 bf16 = 8 MB
  float* out = (float*)d_out;

  if (ws_size < (size_t)(524288 + 8192 * 512 * 2)) return;  // workspace guard

  prep_weights<<<dim3(1024), dim3(256), 0, stream>>>(w1, w2, wp, w1T, w2T, wpT);
  edge_mlp<<<dim3(2048), dim3(256), 0, stream>>>(pos, sup_idx, src_idx, w1T, b1, w2T, b2, cat);
  proj<<<dim3(64, 2), dim3(256), 0, stream>>>(cat, wpT, bp, out);
}

// Round 4
// 118.378 us; speedup vs baseline: 2.5553x; 1.1354x over previous
//
#include <hip/hip_runtime.h>
#include <hip/hip_bf16.h>

#define DEG 32
#define HID 256

typedef __bf16 bf16_t;
typedef bf16_t bf16x8 __attribute__((ext_vector_type(8)));
typedef float f32x16 __attribute__((ext_vector_type(16)));

// 10000^(-i/32), i = 0..31 (compile-time immediates after unroll)
constexpr float OMG[32] = {
    1.0f,           0.74989421f,    0.56234133f,    0.42169650f,
    0.31622777f,    0.23713737f,    0.17782794f,    0.13335214f,
    0.1f,           0.074989421f,   0.056234133f,   0.042169650f,
    0.031622777f,   0.023713737f,   0.017782794f,   0.013335214f,
    0.01f,          0.0074989421f,  0.0056234133f,  0.0042169650f,
    0.0031622777f,  0.0023713737f,  0.0017782794f,  0.0013335214f,
    0.001f,         0.00074989421f, 0.00056234133f, 0.00042169650f,
    0.00031622777f, 0.00023713737f, 0.00017782794f, 0.00013335214f};

__device__ __forceinline__ float gelu_fast(float x) {
  // tanh-form GELU as sigmoid: x * sigma(1.595769*x*(1+0.044715*x^2))
  float u = x * (1.0f + 0.044715f * x * x);
  float e = __expf(-1.5957691216057308f * u);
  return __fdividef(x, 1.0f + e);
}

__device__ __forceinline__ f32x16 mfma_bf16(bf16x8 a, bf16x8 b, f32x16 c) {
  return __builtin_amdgcn_mfma_f32_32x32x16_bf16(a, b, c, 0, 0, 0);
}

// ---- prep A: casts/transposes.
//  w1T[n][k]   = w1[k][n]            (256x256)
//  wpTa[o][n]  = wp[n][o]    n<256   (256x256)  A-operand for prep B
//  wpT2[o][256+kp] = wp[256+kp][o]   (bottom half of fused proj weight)
//  w2b[k][j]   = w2[k][j]            (row-major cast)
__global__ __launch_bounds__(256) void prep_a(
    const float* __restrict__ w1, const float* __restrict__ w2,
    const float* __restrict__ wp,
    bf16_t* __restrict__ w1T, bf16_t* __restrict__ wpTa,
    bf16_t* __restrict__ wpT2, bf16_t* __restrict__ w2b) {
  int tid = blockIdx.x * 256 + threadIdx.x;  // 262144 threads
  if (tid < 65536) {
    int n = tid >> 8, k = tid & 255;
    w1T[tid] = (bf16_t)w1[k * 256 + n];
  } else if (tid < 131072) {
    int t = tid - 65536;
    int o = t >> 8, n = t & 255;
    wpTa[t] = (bf16_t)wp[n * 256 + o];
  } else if (tid < 196608) {
    int t = tid - 131072;
    int o = t >> 8, kp = t & 255;
    wpT2[o * 512 + 256 + kp] = (bf16_t)wp[(256 + kp) * 256 + o];
  } else {
    int t = tid - 196608;
    w2b[t] = (bf16_t)w2[t];
  }
}

// ---- prep B: wpT2[o][j] = W2'[j][o] = sum_n w2[j][n] * wp[n][o]   (j<256)
// D = wpTa (M=o,K=n) @ w2b^T-as-B (col=j, k=n). 128x128 tile per block, grid(2,2).
__global__ __launch_bounds__(256) void prep_b(
    const bf16_t* __restrict__ wpTa, const bf16_t* __restrict__ w2b,
    bf16_t* __restrict__ wpT2) {
  const int tid = threadIdx.x;
  const int l = tid & 63;
  const int w = tid >> 6;
  const int wm = w >> 1, wn = w & 1;
  const int rm = blockIdx.x * 128 + wm * 64;  // o
  const int cn = blockIdx.y * 128 + wn * 64;  // j
  const int asel = l >> 5;
  const int lr = l & 31;
  const int r0 = rm + lr, r1 = rm + 32 + lr;
  const int c0 = cn + lr, c1 = cn + 32 + lr;

  f32x16 a00, a01, a10, a11;
#pragma unroll
  for (int q = 0; q < 16; ++q) { a00[q] = 0.f; a01[q] = 0.f; a10[q] = 0.f; a11[q] = 0.f; }
#pragma unroll 4
  for (int kk = 0; kk < 16; ++kk) {
    int k0 = kk * 16 + 8 * asel;
    bf16x8 fa0 = *(const bf16x8*)(wpTa + r0 * 256 + k0);
    bf16x8 fa1 = *(const bf16x8*)(wpTa + r1 * 256 + k0);
    bf16x8 fb0 = *(const bf16x8*)(w2b + c0 * 256 + k0);
    bf16x8 fb1 = *(const bf16x8*)(w2b + c1 * 256 + k0);
    a00 = mfma_bf16(fa0, fb0, a00);
    a01 = mfma_bf16(fa0, fb1, a01);
    a10 = mfma_bf16(fa1, fb0, a10);
    a11 = mfma_bf16(fa1, fb1, a11);
  }
#pragma unroll
  for (int rr = 0; rr < 16; ++rr) {
    int rowo = (rr & 3) + 8 * (rr >> 2) + 4 * asel;
    wpT2[(rm + rowo) * 512 + c0] = (bf16_t)a00[rr];
    wpT2[(rm + rowo) * 512 + c1] = (bf16_t)a01[rr];
    wpT2[(rm + 32 + rowo) * 512 + c0] = (bf16_t)a10[rr];
    wpT2[(rm + 32 + rowo) * 512 + c1] = (bf16_t)a11[rr];
  }
}

// ---- prep C: bfold[o] = bp[o] + sum_k b2[k] * wp[k][o]
__global__ __launch_bounds__(256) void prep_c(
    const float* __restrict__ b2, const float* __restrict__ wp,
    const float* __restrict__ bp, float* __restrict__ bfold) {
  const int o = threadIdx.x;
  float s = bp[o];
  for (int k = 0; k < 256; ++k) s += b2[k] * wp[k * 256 + o];
  bfold[o] = s;
}

// ---- edge kernel: 4 supernodes/block. embed 128 edges -> mm1 -> gelu+mean.
__global__ __launch_bounds__(256, 2) void edge_mlp(
    const float* __restrict__ pos, const int* __restrict__ sup_idx,
    const int* __restrict__ src_idx,
    const bf16_t* __restrict__ w1T, const float* __restrict__ b1,
    bf16_t* __restrict__ cat) {
  __shared__ __attribute__((aligned(16))) bf16_t A[128 * 256];  // 64 KiB

  const int bid = blockIdx.x;
  const int tid = threadIdx.x;

  // ---- supernode abs-pos embed (ndim=3: 3*84, 42 freqs, 4 pad) -> cat[.,256:512]
  if (tid < 252) {
    const int j = tid;
    const int d = (j >= 84 ? 1 : 0) + (j >= 168 ? 1 : 0);
    const int jj = j - 84 * d;
    const int sc = (jj >= 42) ? 1 : 0;
    const int i = jj - 42 * sc;
    const float om = __expf(-0.21929381838038533f * (float)i);  // ln(1e4)/42
#pragma unroll
    for (int it = 0; it < 4; ++it) {
      const int srow = bid * 4 + it;
      const float p = pos[sup_idx[srow] * 3 + d];
      const float a = p * om;
      const float v = sc ? __cosf(a) : __sinf(a);
      cat[srow * 512 + 256 + j] = (bf16_t)v;
    }
  } else {
#pragma unroll
    for (int it = 0; it < 4; ++it)
      cat[(bid * 4 + it) * 512 + 256 + tid] = (bf16_t)0.0f;  // pad cols 508..511
  }

  // ---- edge relpos embed (ndim=4: 4*64, 32 freqs) into swizzled A
  {
    const int r = tid >> 1;        // edge row 0..127
    const int h = tid & 1;         // column half (0: cols 0-127, 1: 128-255)
    const int e = bid * 128 + r;
    const int srci = src_idx[e];
    const int si = sup_idx[bid * 4 + (r >> 5)];
    const float dx = pos[si * 3 + 0] - pos[srci * 3 + 0];
    const float dy = pos[si * 3 + 1] - pos[srci * 3 + 1];
    const float dz = pos[si * 3 + 2] - pos[srci * 3 + 2];
    const float mg = sqrtf(dx * dx + dy * dy + dz * dz);
    const float rd0 = h ? dz : dx;  // j<8  -> dim 2h
    const float rd1 = h ? mg : dy;  // j>=8 -> dim 2h+1
    char* arow = (char*)A + r * 512;
    const int swz = (r & 31) << 4;
    const int cb0 = h << 4;
#pragma unroll
    for (int j = 0; j < 16; ++j) {
      const float rd = (j < 8) ? rd0 : rd1;
      bf16x8 v8;
#pragma unroll
      for (int je = 0; je < 8; ++je) {
        const float a = rd * OMG[(j & 3) * 8 + je];
        v8[je] = (bf16_t)(((j >> 2) & 1) ? __cosf(a) : __sinf(a));
      }
      *(bf16x8*)(arow + (((cb0 + j) << 4) ^ swz)) = v8;
    }
  }
  __syncthreads();

  const int l = tid & 63, w = tid >> 6;
  const int hi = l >> 5, lc = l & 31;
  const char* Ab = (const char*)A;
  const int abase = lc * 512;
  const int swzl = lc << 4;

  f32x16 acc[4][2];
#pragma unroll
  for (int mt = 0; mt < 4; ++mt)
#pragma unroll
    for (int nt = 0; nt < 2; ++nt)
#pragma unroll
      for (int q = 0; q < 16; ++q) acc[mt][nt][q] = 0.0f;

  // ---- mm1: A(128x256) @ w1 ; wave w owns cols [64w, 64w+64)
  {
    const bf16_t* bp0 = w1T + (64 * w + lc) * 256 + 8 * hi;
    const bf16_t* bp1 = bp0 + 32 * 256;
#pragma unroll
    for (int kk = 0; kk < 16; ++kk) {
      const int koff = abase + ((kk * 32 + hi * 16) ^ swzl);
      bf16x8 a0 = *(const bf16x8*)(Ab + koff);
      bf16x8 a1 = *(const bf16x8*)(Ab + koff + 16384);
      bf16x8 a2 = *(const bf16x8*)(Ab + koff + 32768);
      bf16x8 a3 = *(const bf16x8*)(Ab + koff + 49152);
      bf16x8 f0 = *(const bf16x8*)(bp0 + kk * 16);
      bf16x8 f1 = *(const bf16x8*)(bp1 + kk * 16);
      acc[0][0] = mfma_bf16(a0, f0, acc[0][0]);
      acc[0][1] = mfma_bf16(a0, f1, acc[0][1]);
      acc[1][0] = mfma_bf16(a1, f0, acc[1][0]);
      acc[1][1] = mfma_bf16(a1, f1, acc[1][1]);
      acc[2][0] = mfma_bf16(a2, f0, acc[2][0]);
      acc[2][1] = mfma_bf16(a2, f1, acc[2][1]);
      acc[3][0] = mfma_bf16(a3, f0, acc[3][0]);
      acc[3][1] = mfma_bf16(a3, f1, acc[3][1]);
    }
  }

  // ---- gelu + segment mean (exactly 32 edges/supernode) -> cat[.,0:256]
  // (b2 and the agg@wp projection are folded into wpT2/bfold; only b1 here.)
  {
    const float bi0 = b1[64 * w + lc], bi1 = b1[64 * w + 32 + lc];
#pragma unroll
    for (int mt = 0; mt < 4; ++mt) {
      float s0 = 0.0f, s1 = 0.0f;
#pragma unroll
      for (int q = 0; q < 16; ++q) {
        s0 += gelu_fast(acc[mt][0][q] + bi0);
        s1 += gelu_fast(acc[mt][1][q] + bi1);
      }
      s0 += __shfl_xor(s0, 32);
      s1 += __shfl_xor(s1, 32);
      if (l < 32) {
        const int srow = bid * 4 + mt;
        cat[srow * 512 + 64 * w + lc] = (bf16_t)(s0 * 0.03125f);
        cat[srow * 512 + 64 * w + 32 + lc] = (bf16_t)(s1 * 0.03125f);
      }
    }
  }
}

// ---- fused projection: out = cat(8192x512) @ wpT2^T + bfold  -> fp32
__global__ __launch_bounds__(256) void proj(
    const bf16_t* __restrict__ cat, const bf16_t* __restrict__ wpT2,
    const float* __restrict__ bfold, float* __restrict__ out) {
  const int bx = blockIdx.x;  // 64 row-blocks of 128
  const int by = blockIdx.y;  // 2 col-blocks of 128
  const int tid = threadIdx.x;
  const int l = tid & 63;
  const int w = tid >> 6;
  const int wm = w >> 1, wn = w & 1;
  const int rm = bx * 128 + wm * 64;
  const int cn = by * 128 + wn * 64;
  const int asel = l >> 5;
  const int lr = l & 31;

  const int r0 = rm + lr, r1 = rm + 32 + lr;
  const int c0 = cn + lr, c1 = cn + 32 + lr;

  f32x16 a00, a01, a10, a11;
#pragma unroll
  for (int q = 0; q < 16; ++q) { a00[q] = 0.f; a01[q] = 0.f; a10[q] = 0.f; a11[q] = 0.f; }
#pragma unroll 4
  for (int kk = 0; kk < 32; ++kk) {
    int k0 = kk * 16 + 8 * asel;
    bf16x8 fa0 = *(const bf16x8*)(cat + r0 * 512 + k0);
    bf16x8 fa1 = *(const bf16x8*)(cat + r1 * 512 + k0);
    bf16x8 fb0 = *(const bf16x8*)(wpT2 + c0 * 512 + k0);
    bf16x8 fb1 = *(const bf16x8*)(wpT2 + c1 * 512 + k0);
    a00 = mfma_bf16(fa0, fb0, a00);
    a01 = mfma_bf16(fa0, fb1, a01);
    a10 = mfma_bf16(fa1, fb0, a10);
    a11 = mfma_bf16(fa1, fb1, a11);
  }
  float bias0 = bfold[c0], bias1 = bfold[c1];
#pragma unroll
  for (int rr = 0; rr < 16; ++rr) {
    int rowo = (rr & 3) + 8 * (rr >> 2) + 4 * asel;
    out[(rm + rowo) * 256 + c0] = a00[rr] + bias0;
    out[(rm + rowo) * 256 + c1] = a01[rr] + bias1;
    out[(rm + 32 + rowo) * 256 + c0] = a10[rr] + bias0;
    out[(rm + 32 + rowo) * 256 + c1] = a11[rr] + bias1;
  }
}

extern "C" void kernel_launch(void* const* d_in, const int* in_sizes, int n_in,
                              void* d_out, int out_size, void* d_ws, size_t ws_size,
                              hipStream_t stream) {
  const float* pos = (const float*)d_in[0];
  const int* sup_idx = (const int*)d_in[1];
  const int* src_idx = (const int*)d_in[2];
  // d_in[3] = dst_seg: repeat(arange(NSUP), DEG) by construction; not needed
  const float* w1 = (const float*)d_in[4];
  const float* b1 = (const float*)d_in[5];
  const float* w2 = (const float*)d_in[6];
  const float* b2 = (const float*)d_in[7];
  const float* wp = (const float*)d_in[8];
  const float* bp = (const float*)d_in[9];

  char* ws = (char*)d_ws;
  bf16_t* w1T  = (bf16_t*)(ws);            // 128 KB
  bf16_t* w2b  = (bf16_t*)(ws + 131072);   // 128 KB
  bf16_t* wpTa = (bf16_t*)(ws + 262144);   // 128 KB
  bf16_t* wpT2 = (bf16_t*)(ws + 393216);   // 256 KB (256 x 512)
  float*  bfold = (float*)(ws + 655360);   // 1 KB
  bf16_t* cat  = (bf16_t*)(ws + 659456);   // 8192*512 bf16 = 8 MB
  float* out = (float*)d_out;

  if (ws_size < (size_t)(659456 + 8192 * 512 * 2)) return;  // workspace guard

  prep_a<<<dim3(1024), dim3(256), 0, stream>>>(w1, w2, wp, w1T, wpTa, wpT2, w2b);
  prep_b<<<dim3(2, 2), dim3(256), 0, stream>>>(wpTa, w2b, wpT2);
  prep_c<<<dim3(1), dim3(256), 0, stream>>>(b2, wp, bp, bfold);
  edge_mlp<<<dim3(2048), dim3(256), 0, stream>>>(pos, sup_idx, src_idx, w1T, b1, cat);
  proj<<<dim3(64, 2), dim3(256), 0, stream>>>(cat, wpT2, bfold, out);
}